// Round 5
// baseline (631.549 us; speedup 1.0000x reference)
//
#include <hip/hip_runtime.h>
#include <stdint.h>

#define B_ 8
#define C_ 256
#define N_ 4096
#define CQK 32

typedef __attribute__((ext_vector_type(8))) _Float16 f16x8;
typedef __attribute__((ext_vector_type(2))) _Float16 f16x2;
typedef __attribute__((ext_vector_type(4))) float f32x4;

#define LOG2E 1.4426950408889634f

// ---------------------------------------------------------------------------
// Kernel 1: transpose x [b][c][n] fp32 -> xT [b][n][c] fp16 (c contiguous).
// xT lives in d_out[0:16.78MB]; dead after proj_gemm, then attn overwrites
// d_out with y (round-2-proven usage pattern).
// ---------------------------------------------------------------------------
__global__ __launch_bounds__(256) void xpose_kernel(
    const float* __restrict__ x, _Float16* __restrict__ xT)
{
  __shared__ float xs[64 * 129];
  const int t  = threadIdx.x;
  const int blk = blockIdx.x;
  const int nt = blk & 31;          // n-tile (128 px)
  const int ct = (blk >> 5) & 3;    // c-tile (64 ch)
  const int b  = blk >> 7;
  const int c0 = ct * 64, n0 = nt * 128;

  #pragma unroll
  for (int p = 0; p < 8; ++p) {
    int cc = p * 8 + (t >> 5);
    int nn = (t & 31) * 4;
    float4 v = *(const float4*)(x + ((size_t)(b * C_ + c0 + cc)) * N_ + n0 + nn);
    xs[cc * 129 + nn]     = v.x;
    xs[cc * 129 + nn + 1] = v.y;
    xs[cc * 129 + nn + 2] = v.z;
    xs[cc * 129 + nn + 3] = v.w;
  }
  __syncthreads();
  #pragma unroll
  for (int p = 0; p < 4; ++p) {
    int id = p * 256 + t;
    int cchunk = id & 7, n = id >> 3;
    _Float16 h[8];
    #pragma unroll
    for (int j = 0; j < 8; ++j) h[j] = (_Float16)xs[(cchunk * 8 + j) * 129 + n];
    *(f16x8*)(xT + ((size_t)(b * N_) + n0 + n) * C_ + c0 + cchunk * 8) = *(f16x8*)h;
  }
}

// ---------------------------------------------------------------------------
// Kernel 2: weights -> fp16 Wcat[320][256] (0-31 wq, 32-63 wk, 64-319 wv).
// ---------------------------------------------------------------------------
__global__ __launch_bounds__(256) void wconv_kernel(
    const float* __restrict__ wq, const float* __restrict__ wk,
    const float* __restrict__ wv, _Float16* __restrict__ wf)
{
  int idx = blockIdx.x * 256 + threadIdx.x;
  int e = idx * 4;
  int o = e >> 8, c = e & 255;
  const float* src;
  if (o < 32)      src = wq + o * 256 + c;
  else if (o < 64) src = wk + (o - 32) * 256 + c;
  else             src = wv + (o - 64) * 256 + c;
  float4 v = *(const float4*)src;
  _Float16 h[4] = {(_Float16)v.x, (_Float16)v.y, (_Float16)v.z, (_Float16)v.w};
  *(uint2*)(wf + e) = *(uint2*)h;
}

// ---------------------------------------------------------------------------
// Kernel 3: projection GEMM (fp16 MFMA). q stored pre-scaled by log2(e).
// All outputs (qf, kf, vfp) go to d_ws.
// ---------------------------------------------------------------------------
__global__ __launch_bounds__(256, 4) void proj_gemm_kernel(
    const _Float16* __restrict__ xT, const _Float16* __restrict__ wf,
    const float* __restrict__ bq, const float* __restrict__ bk,
    const float* __restrict__ bv,
    _Float16* __restrict__ qf, _Float16* __restrict__ kf,
    _Float16* __restrict__ vout)
{
  const int t = threadIdx.x, lane = t & 63;
  const int w = t >> 6;
  const int l15 = lane & 15, q4 = lane >> 4;
  const int blk = blockIdx.x;
  const int otile = blk % 5;          // 0 = q/k, 1..4 = v
  const int nt = blk / 5;
  const int b  = nt >> 5;
  const int n0 = (nt & 31) * 128;
  const int o0w = (w & 1) * 32;
  const int n0w = (w >> 1) * 64;

  f32x4 acc[2][4];
  const f32x4 zf = {0.f, 0.f, 0.f, 0.f};
  #pragma unroll
  for (int a = 0; a < 2; ++a)
    #pragma unroll
    for (int bb = 0; bb < 4; ++bb) acc[a][bb] = zf;

  const _Float16* wbase = wf + (size_t)(otile * 64 + o0w) * 256;
  const _Float16* xbase = xT + ((size_t)(b * N_) + n0 + n0w) * C_;

  #pragma unroll
  for (int kc = 0; kc < 8; ++kc) {
    f16x8 af[2], bfr[4];
    #pragma unroll
    for (int ob = 0; ob < 2; ++ob)
      af[ob] = *(const f16x8*)(wbase + (ob * 16 + l15) * 256 + kc * 32 + q4 * 8);
    #pragma unroll
    for (int nb = 0; nb < 4; ++nb)
      bfr[nb] = *(const f16x8*)(xbase + (nb * 16 + l15) * 256 + kc * 32 + q4 * 8);
    #pragma unroll
    for (int ob = 0; ob < 2; ++ob)
      #pragma unroll
      for (int nb = 0; nb < 4; ++nb)
        acc[ob][nb] = __builtin_amdgcn_mfma_f32_16x16x32_f16(af[ob], bfr[nb], acc[ob][nb], 0, 0, 0);
  }

  if (otile == 0) {
    _Float16* dst = (o0w == 0) ? qf : kf;
    const float* bias = (o0w == 0) ? bq : bk;
    const float scl = (o0w == 0) ? LOG2E : 1.0f;   // fold log2(e) into q
    #pragma unroll
    for (int ob = 0; ob < 2; ++ob) {
      float4 b4 = *(const float4*)(bias + ob * 16 + q4 * 4);
      #pragma unroll
      for (int nb = 0; nb < 4; ++nb) {
        int pixel = n0 + n0w + nb * 16 + l15;
        _Float16 h[4];
        h[0] = (_Float16)((acc[ob][nb][0] + b4.x) * scl);
        h[1] = (_Float16)((acc[ob][nb][1] + b4.y) * scl);
        h[2] = (_Float16)((acc[ob][nb][2] + b4.z) * scl);
        h[3] = (_Float16)((acc[ob][nb][3] + b4.w) * scl);
        *(uint2*)(dst + ((size_t)(b * N_) + pixel) * CQK + ob * 16 + q4 * 4) = *(uint2*)h;
      }
    }
  } else {
    int cbase = (otile - 1) * 64 + o0w;
    #pragma unroll
    for (int ob = 0; ob < 2; ++ob) {
      float4 b4 = *(const float4*)(bv + cbase + ob * 16 + q4 * 4);
      #pragma unroll
      for (int nb = 0; nb < 4; ++nb) {
        int pixel = n0 + n0w + nb * 16 + l15;
        #pragma unroll
        for (int r = 0; r < 4; ++r) {
          int c = cbase + ob * 16 + q4 * 4 + r;
          float bval = (r == 0) ? b4.x : (r == 1) ? b4.y : (r == 2) ? b4.z : b4.w;
          vout[((size_t)(b * C_) + c) * N_ + pixel] = (_Float16)(acc[ob][nb][r] + bval);
        }
      }
    }
  }
}

// ---------------------------------------------------------------------------
// Kernel 4: flash attention + residual, barrier-free K-loop.
// 512 thr (8 waves), M=128 q/block, grid 256 (b = blk&7 -> XCD-local K/V).
// Wave owns 16 query rows x all 256 channels; softmax in-wave (2 shuffles);
// P wave-private LDS. Writes y = gamma*attn + x as FP32 to d_out.
// ---------------------------------------------------------------------------
__global__ __launch_bounds__(512, 2) void attn_kernel(
    const float* __restrict__ x, const float* __restrict__ gptr,
    const _Float16* __restrict__ qf, const _Float16* __restrict__ kf,
    const _Float16* __restrict__ vf, float* __restrict__ yout)
{
  __shared__ __align__(16) char smem[8 * 2304];   // per-wave 16 rows x 144 B
  const int t = threadIdx.x, lane = t & 63;
  const int w = t >> 6;
  const int l15 = lane & 15, q4 = lane >> 4;
  const int b  = blockIdx.x & 7;
  const int i0 = (blockIdx.x >> 3) * 128;
  const int myrow = w * 16;                       // wave's first query row
  char* Pw = smem + w * 2304;

  // Q B-frag (row i = l15 within wave's 16): stays in regs whole kernel
  const f16x8 qfr = *(const f16x8*)(qf + ((size_t)(b * N_) + i0 + myrow + l15) * CQK + q4 * 8);

  const _Float16* kb = kf + (size_t)b * N_ * CQK;
  const _Float16* vb = vf + (size_t)b * C_ * N_;

  f32x4 acc[16];
  const f32x4 zf = {0.f, 0.f, 0.f, 0.f};
  #pragma unroll
  for (int ct = 0; ct < 16; ++ct) acc[ct] = zf;

  float mold = -1e30f, lrun = 0.f;

  // preload K frags for jt=0 (A-operand: lane l15 = j, q4*8+r = c')
  f16x8 kcur[4];
  #pragma unroll
  for (int jb = 0; jb < 4; ++jb)
    kcur[jb] = *(const f16x8*)(kb + (size_t)(jb * 16 + l15) * CQK + q4 * 8);

  for (int jt = 0; jt < N_ / 64; ++jt) {
    const int jbase = jt * 64;

    // ---- S: 16 j-values per lane, all for row i = l15 ----
    f32x4 sv[4];
    #pragma unroll
    for (int jb = 0; jb < 4; ++jb)
      sv[jb] = __builtin_amdgcn_mfma_f32_16x16x32_f16(kcur[jb], qfr, zf, 0, 0, 0);

    // prefetch next K tile (last iter wraps to tile 0: harmless, unused)
    const int jnext = (jt == N_ / 64 - 1) ? 0 : jbase + 64;
    #pragma unroll
    for (int jb = 0; jb < 4; ++jb)
      kcur[jb] = *(const f16x8*)(kb + (size_t)(jnext + jb * 16 + l15) * CQK + q4 * 8);

    // ---- in-wave online softmax (scores already in log2 units) ----
    float lm = fmaxf(fmaxf(fmaxf(sv[0][0], sv[0][1]), fmaxf(sv[0][2], sv[0][3])),
                     fmaxf(fmaxf(sv[1][0], sv[1][1]), fmaxf(sv[1][2], sv[1][3])));
    lm = fmaxf(lm, fmaxf(fmaxf(fmaxf(sv[2][0], sv[2][1]), fmaxf(sv[2][2], sv[2][3])),
                         fmaxf(fmaxf(sv[3][0], sv[3][1]), fmaxf(sv[3][2], sv[3][3]))));
    lm = fmaxf(lm, __shfl_xor(lm, 16));
    lm = fmaxf(lm, __shfl_xor(lm, 32));
    float mnew = fmaxf(mold, lm);
    bool upd = mnew > mold;
    float alpha = __builtin_amdgcn_exp2f(mold - mnew);

    float p[4][4];
    float ts = 0.f;
    #pragma unroll
    for (int jb = 0; jb < 4; ++jb)
      #pragma unroll
      for (int r = 0; r < 4; ++r) {
        float pv = __builtin_amdgcn_exp2f(sv[jb][r] - mnew);
        p[jb][r] = pv; ts += pv;
      }
    ts += __shfl_xor(ts, 16);
    ts += __shfl_xor(ts, 32);
    lrun = lrun * alpha + ts;
    mold = mnew;

    // ---- P -> wave-private LDS (row l15, cols jb*16 + q4*4 + r) ----
    #pragma unroll
    for (int jb = 0; jb < 4; ++jb) {
      uint2 pk;
      pk.x = __builtin_bit_cast(unsigned, __builtin_amdgcn_cvt_pkrtz(p[jb][0], p[jb][1]));
      pk.y = __builtin_bit_cast(unsigned, __builtin_amdgcn_cvt_pkrtz(p[jb][2], p[jb][3]));
      *(uint2*)(Pw + l15 * 144 + jb * 32 + q4 * 8) = pk;
    }

    // ---- rescale accumulators (alpha == 1 for non-updated rows) ----
    if (__any(upd)) {
      #pragma unroll
      for (int ct = 0; ct < 16; ++ct)
        #pragma unroll
        for (int r = 0; r < 4; ++r) acc[ct][r] *= alpha;
    }

    // ---- PV: acc[c-tile] += V x P (P read: B-frag, same wave's writes) ----
    #pragma unroll
    for (int ks = 0; ks < 2; ++ks) {
      f16x8 pf = *(const f16x8*)(Pw + l15 * 144 + ks * 64 + q4 * 16);
      #pragma unroll
      for (int ct = 0; ct < 16; ++ct) {
        f16x8 vfr = *(const f16x8*)(vb + (size_t)(ct * 16 + l15) * N_ + jbase + ks * 32 + q4 * 8);
        acc[ct] = __builtin_amdgcn_mfma_f32_16x16x32_f16(vfr, pf, acc[ct], 0, 0, 0);
      }
    }
  }

  // ---- epilogue: O /= l; y = gamma*O + x (fp32 to d_out) ----
  const float gamma = gptr[0];
  float linv = 1.0f / lrun;          // per-lane == per-row (row = l15)
  const int i = i0 + myrow + l15;
  #pragma unroll
  for (int ct = 0; ct < 16; ++ct) {
    #pragma unroll
    for (int r = 0; r < 4; ++r) {
      int c = ct * 16 + q4 * 4 + r;
      size_t off = ((size_t)(b * C_) + c) * N_ + i;
      float o = acc[ct][r] * linv;
      yout[off] = fmaf(gamma, o, x[off]);
    }
  }
}

// ---------------------------------------------------------------------------
// Kernel 5: BN statistics from fp32 y (d_out); one 1024-thr block per channel.
// ---------------------------------------------------------------------------
__global__ __launch_bounds__(1024) void bnstats_kernel(
    const float* __restrict__ y, float* __restrict__ meanw, float* __restrict__ rstdw)
{
  const int c = blockIdx.x;
  const int t = threadIdx.x;
  float s1 = 0.f, s2 = 0.f;
  #pragma unroll
  for (int b = 0; b < B_; ++b) {
    float4 v = *(const float4*)(y + ((size_t)(b * C_ + c)) * N_ + t * 4);
    s1 += v.x + v.y + v.z + v.w;
    s2 += v.x * v.x + v.y * v.y + v.z * v.z + v.w * v.w;
  }
  #pragma unroll
  for (int off = 1; off < 64; off <<= 1) {
    s1 += __shfl_xor(s1, off);
    s2 += __shfl_xor(s2, off);
  }
  __shared__ float r1[16], r2[16];
  const int wid = t >> 6;
  if ((t & 63) == 0) { r1[wid] = s1; r2[wid] = s2; }
  __syncthreads();
  if (t == 0) {
    float a1 = 0.f, a2 = 0.f;
    #pragma unroll
    for (int k = 0; k < 16; ++k) { a1 += r1[k]; a2 += r2[k]; }
    float mean = a1 * (1.0f / 32768.0f);
    float var  = a2 * (1.0f / 32768.0f) - mean * mean;
    meanw[c] = mean;
    rstdw[c] = rsqrtf(var + 1e-5f);
  }
}

// ---------------------------------------------------------------------------
// Kernel 6: BN normalize + ReLU, in-place fp32 on d_out.
// ---------------------------------------------------------------------------
__global__ __launch_bounds__(256) void bnapply_kernel(
    float* __restrict__ y,
    const float* __restrict__ meanw, const float* __restrict__ rstdw,
    const float* __restrict__ bnw, const float* __restrict__ bnb)
{
  size_t idx = (size_t)blockIdx.x * 256 + threadIdx.x;   // 1,048,576 threads
  size_t el = idx * 8;
  int c = (int)((el >> 12) & 255);
  float sc = bnw[c] * rstdw[c];
  float sh = fmaf(-meanw[c], sc, bnb[c]);
  float4 v0 = *(const float4*)(y + el);
  float4 v1 = *(const float4*)(y + el + 4);
  v0.x = fmaxf(fmaf(v0.x, sc, sh), 0.f);
  v0.y = fmaxf(fmaf(v0.y, sc, sh), 0.f);
  v0.z = fmaxf(fmaf(v0.z, sc, sh), 0.f);
  v0.w = fmaxf(fmaf(v0.w, sc, sh), 0.f);
  v1.x = fmaxf(fmaf(v1.x, sc, sh), 0.f);
  v1.y = fmaxf(fmaf(v1.y, sc, sh), 0.f);
  v1.z = fmaxf(fmaf(v1.z, sc, sh), 0.f);
  v1.w = fmaxf(fmaf(v1.w, sc, sh), 0.f);
  *(float4*)(y + el) = v0;
  *(float4*)(y + el + 4) = v1;
}

extern "C" void kernel_launch(void* const* d_in, const int* in_sizes, int n_in,
                              void* d_out, int out_size, void* d_ws, size_t ws_size,
                              hipStream_t stream)
{
  const float* x   = (const float*)d_in[0];
  const float* wq  = (const float*)d_in[1];
  const float* bq  = (const float*)d_in[2];
  const float* wk  = (const float*)d_in[3];
  const float* bk  = (const float*)d_in[4];
  const float* bv  = (const float*)d_in[6];
  const float* wv  = (const float*)d_in[5];
  const float* gm  = (const float*)d_in[7];
  const float* bnw = (const float*)d_in[8];
  const float* bnb = (const float*)d_in[9];

  // d_out: xT fp16 [0:16.78MB] during stages 1-3 (round-2-proven pattern),
  // then y fp32 (full 33.55MB) written by attn, normalized in place.
  _Float16* xT = (_Float16*)d_out;
  float* y = (float*)d_out;

  // ws (~22.01 MB): qf [0,2M) | kf [2M,4M) | vfp [4M,20.78M) | wf [21M,+160K)
  //                 meanw [22M,+1K) | rstdw [22M+4096,+1K)
  char* ws = (char*)d_ws;
  _Float16* qf  = (_Float16*)(ws);
  _Float16* kf  = (_Float16*)(ws + ((size_t)2 << 20));
  _Float16* vfp = (_Float16*)(ws + ((size_t)4 << 20));
  _Float16* wf  = (_Float16*)(ws + ((size_t)21 << 20));
  float* meanw  = (float*)(ws + ((size_t)22 << 20));
  float* rstdw  = (float*)(ws + ((size_t)22 << 20) + 4096);

  hipLaunchKernelGGL(xpose_kernel, dim3(1024), dim3(256), 0, stream, x, xT);
  hipLaunchKernelGGL(wconv_kernel, dim3(80), dim3(256), 0, stream, wq, wk, wv, wf);
  hipLaunchKernelGGL(proj_gemm_kernel, dim3(1280), dim3(256), 0, stream,
                     xT, wf, bq, bk, bv, qf, kf, vfp);
  hipLaunchKernelGGL(attn_kernel, dim3(256), dim3(512), 0, stream,
                     x, gm, qf, kf, vfp, y);
  hipLaunchKernelGGL(bnstats_kernel, dim3(256), dim3(1024), 0, stream,
                     y, meanw, rstdw);
  hipLaunchKernelGGL(bnapply_kernel, dim3(4096), dim3(256), 0, stream,
                     y, meanw, rstdw, bnw, bnb);
}

// Round 6
// 333.627 us; speedup vs baseline: 1.8930x; 1.8930x over previous
//
#include <hip/hip_runtime.h>
#include <stdint.h>

#define B_ 8
#define C_ 256
#define N_ 4096
#define CQK 32

typedef __attribute__((ext_vector_type(8))) _Float16 f16x8;
typedef __attribute__((ext_vector_type(2))) _Float16 f16x2;
typedef __attribute__((ext_vector_type(4))) float f32x4;

#define LOG2E 1.4426950408889634f

// ---------------------------------------------------------------------------
// Kernel 1: transpose x [b][c][n] fp32 -> xT [b][n][c] fp16 (c contiguous).
// xT lives in d_out[0:16.78MB]; dead after proj_gemm (attn then overwrites
// d_out with y). Round-2/5-proven pattern.
// ---------------------------------------------------------------------------
__global__ __launch_bounds__(256) void xpose_kernel(
    const float* __restrict__ x, _Float16* __restrict__ xT)
{
  __shared__ float xs[64 * 129];
  const int t  = threadIdx.x;
  const int blk = blockIdx.x;
  const int nt = blk & 31;          // n-tile (128 px)
  const int ct = (blk >> 5) & 3;    // c-tile (64 ch)
  const int b  = blk >> 7;
  const int c0 = ct * 64, n0 = nt * 128;

  #pragma unroll
  for (int p = 0; p < 8; ++p) {
    int cc = p * 8 + (t >> 5);
    int nn = (t & 31) * 4;
    float4 v = *(const float4*)(x + ((size_t)(b * C_ + c0 + cc)) * N_ + n0 + nn);
    xs[cc * 129 + nn]     = v.x;
    xs[cc * 129 + nn + 1] = v.y;
    xs[cc * 129 + nn + 2] = v.z;
    xs[cc * 129 + nn + 3] = v.w;
  }
  __syncthreads();
  #pragma unroll
  for (int p = 0; p < 4; ++p) {
    int id = p * 256 + t;
    int cchunk = id & 7, n = id >> 3;
    _Float16 h[8];
    #pragma unroll
    for (int j = 0; j < 8; ++j) h[j] = (_Float16)xs[(cchunk * 8 + j) * 129 + n];
    *(f16x8*)(xT + ((size_t)(b * N_) + n0 + n) * C_ + c0 + cchunk * 8) = *(f16x8*)h;
  }
}

// ---------------------------------------------------------------------------
// Kernel 2: weights -> fp16 Wcat[320][256] (0-31 wq, 32-63 wk, 64-319 wv).
// ---------------------------------------------------------------------------
__global__ __launch_bounds__(256) void wconv_kernel(
    const float* __restrict__ wq, const float* __restrict__ wk,
    const float* __restrict__ wv, _Float16* __restrict__ wf)
{
  int idx = blockIdx.x * 256 + threadIdx.x;
  int e = idx * 4;
  int o = e >> 8, c = e & 255;
  const float* src;
  if (o < 32)      src = wq + o * 256 + c;
  else if (o < 64) src = wk + (o - 32) * 256 + c;
  else             src = wv + (o - 64) * 256 + c;
  float4 v = *(const float4*)src;
  _Float16 h[4] = {(_Float16)v.x, (_Float16)v.y, (_Float16)v.z, (_Float16)v.w};
  *(uint2*)(wf + e) = *(uint2*)h;
}

// ---------------------------------------------------------------------------
// Kernel 3: projection GEMM (fp16 MFMA). q stored pre-scaled by log2(e).
// Outputs (qf, kf, vfp) in d_ws.
// ---------------------------------------------------------------------------
__global__ __launch_bounds__(256, 4) void proj_gemm_kernel(
    const _Float16* __restrict__ xT, const _Float16* __restrict__ wf,
    const float* __restrict__ bq, const float* __restrict__ bk,
    const float* __restrict__ bv,
    _Float16* __restrict__ qf, _Float16* __restrict__ kf,
    _Float16* __restrict__ vout)
{
  const int t = threadIdx.x, lane = t & 63;
  const int w = t >> 6;
  const int l15 = lane & 15, q4 = lane >> 4;
  const int blk = blockIdx.x;
  const int otile = blk % 5;          // 0 = q/k, 1..4 = v
  const int nt = blk / 5;
  const int b  = nt >> 5;
  const int n0 = (nt & 31) * 128;
  const int o0w = (w & 1) * 32;
  const int n0w = (w >> 1) * 64;

  f32x4 acc[2][4];
  const f32x4 zf = {0.f, 0.f, 0.f, 0.f};
  #pragma unroll
  for (int a = 0; a < 2; ++a)
    #pragma unroll
    for (int bb = 0; bb < 4; ++bb) acc[a][bb] = zf;

  const _Float16* wbase = wf + (size_t)(otile * 64 + o0w) * 256;
  const _Float16* xbase = xT + ((size_t)(b * N_) + n0 + n0w) * C_;

  #pragma unroll
  for (int kc = 0; kc < 8; ++kc) {
    f16x8 af[2], bfr[4];
    #pragma unroll
    for (int ob = 0; ob < 2; ++ob)
      af[ob] = *(const f16x8*)(wbase + (ob * 16 + l15) * 256 + kc * 32 + q4 * 8);
    #pragma unroll
    for (int nb = 0; nb < 4; ++nb)
      bfr[nb] = *(const f16x8*)(xbase + (nb * 16 + l15) * 256 + kc * 32 + q4 * 8);
    #pragma unroll
    for (int ob = 0; ob < 2; ++ob)
      #pragma unroll
      for (int nb = 0; nb < 4; ++nb)
        acc[ob][nb] = __builtin_amdgcn_mfma_f32_16x16x32_f16(af[ob], bfr[nb], acc[ob][nb], 0, 0, 0);
  }

  if (otile == 0) {
    _Float16* dst = (o0w == 0) ? qf : kf;
    const float* bias = (o0w == 0) ? bq : bk;
    const float scl = (o0w == 0) ? LOG2E : 1.0f;   // fold log2(e) into q
    #pragma unroll
    for (int ob = 0; ob < 2; ++ob) {
      float4 b4 = *(const float4*)(bias + ob * 16 + q4 * 4);
      #pragma unroll
      for (int nb = 0; nb < 4; ++nb) {
        int pixel = n0 + n0w + nb * 16 + l15;
        _Float16 h[4];
        h[0] = (_Float16)((acc[ob][nb][0] + b4.x) * scl);
        h[1] = (_Float16)((acc[ob][nb][1] + b4.y) * scl);
        h[2] = (_Float16)((acc[ob][nb][2] + b4.z) * scl);
        h[3] = (_Float16)((acc[ob][nb][3] + b4.w) * scl);
        *(uint2*)(dst + ((size_t)(b * N_) + pixel) * CQK + ob * 16 + q4 * 4) = *(uint2*)h;
      }
    }
  } else {
    int cbase = (otile - 1) * 64 + o0w;
    #pragma unroll
    for (int ob = 0; ob < 2; ++ob) {
      float4 b4 = *(const float4*)(bv + cbase + ob * 16 + q4 * 4);
      #pragma unroll
      for (int nb = 0; nb < 4; ++nb) {
        int pixel = n0 + n0w + nb * 16 + l15;
        #pragma unroll
        for (int r = 0; r < 4; ++r) {
          int c = cbase + ob * 16 + q4 * 4 + r;
          float bval = (r == 0) ? b4.x : (r == 1) ? b4.y : (r == 2) ? b4.z : b4.w;
          vout[((size_t)(b * C_) + c) * N_ + pixel] = (_Float16)(acc[ob][nb][r] + bval);
        }
      }
    }
  }
}

// ---------------------------------------------------------------------------
// Kernel 4: flash attention + residual.
// 256 thr (4 waves), M=64 q/block, grid 512 = 2 blocks/CU (b = blk&7 -> XCD-
// local K/V). S-phase: wave owns 16 complete query rows (in-wave softmax,
// validated r5). PV-phase: wave owns c-strip of 64 x ALL 64 i -> each V frag
// (global, L1-resident tile) feeds 4 MFMAs; P+alpha cross waves via double-
// buffered LDS -> ONE barrier per iteration.
// ---------------------------------------------------------------------------
__global__ __launch_bounds__(256, 2) void attn_kernel(
    const float* __restrict__ x, const float* __restrict__ gptr,
    const _Float16* __restrict__ qf, const _Float16* __restrict__ kf,
    const _Float16* __restrict__ vf, float* __restrict__ yout)
{
  // LDS: P ping-pong 2 x (64 rows x 144 B) | alpha 2 x 64 f32 | lrow 64 f32
  __shared__ __align__(16) char smem[2 * 9216 + 2 * 256 + 256];
  float* alph  = (float*)(smem + 18432);
  float* lrowl = (float*)(smem + 18944);

  const int t = threadIdx.x, lane = t & 63;
  const int w = t >> 6;                  // 4 waves
  const int l15 = lane & 15, q4 = lane >> 4;
  const int b  = blockIdx.x & 7;
  const int i0 = (blockIdx.x >> 3) * 64;
  const int myrow = w * 16;              // wave's 16 query rows (S phase)

  // Q B-frag: lane -> i = l15 (wave's rows), k = q4*8+j
  const f16x8 qfr = *(const f16x8*)(qf + ((size_t)(b * N_) + i0 + myrow + l15) * CQK + q4 * 8);

  const _Float16* kb = kf + (size_t)b * N_ * CQK;
  const _Float16* vb = vf + (size_t)b * C_ * N_;

  // PV acc: c = w*64 + ct*16 + q4*4 + r, i = ib*16 + l15
  f32x4 acc[4][4];
  const f32x4 zf = {0.f, 0.f, 0.f, 0.f};
  #pragma unroll
  for (int a = 0; a < 4; ++a)
    #pragma unroll
    for (int bb = 0; bb < 4; ++bb) acc[a][bb] = zf;

  float mold = -1e30f, lrun = 0.f;

  // preload K frags (A-operand: l15 = j, q4*8+r = c')
  f16x8 kcur[4];
  #pragma unroll
  for (int jb = 0; jb < 4; ++jb)
    kcur[jb] = *(const f16x8*)(kb + (size_t)(jb * 16 + l15) * CQK + q4 * 8);

  for (int jt = 0; jt < N_ / 64; ++jt) {
    const int jbase = jt * 64;
    char* Pcur = smem + (jt & 1) * 9216;
    float* acur = alph + (jt & 1) * 64;

    // ---- S: wave's 16 rows x 64 j ----
    f32x4 sv[4];
    #pragma unroll
    for (int jb = 0; jb < 4; ++jb)
      sv[jb] = __builtin_amdgcn_mfma_f32_16x16x32_f16(kcur[jb], qfr, zf, 0, 0, 0);

    // prefetch next K tile (last iter wraps to 0: harmless)
    const int jnext = (jt == N_ / 64 - 1) ? 0 : jbase + 64;
    #pragma unroll
    for (int jb = 0; jb < 4; ++jb)
      kcur[jb] = *(const f16x8*)(kb + (size_t)(jnext + jb * 16 + l15) * CQK + q4 * 8);

    // ---- in-wave online softmax (log2 domain) ----
    float lm = fmaxf(fmaxf(fmaxf(sv[0][0], sv[0][1]), fmaxf(sv[0][2], sv[0][3])),
                     fmaxf(fmaxf(sv[1][0], sv[1][1]), fmaxf(sv[1][2], sv[1][3])));
    lm = fmaxf(lm, fmaxf(fmaxf(fmaxf(sv[2][0], sv[2][1]), fmaxf(sv[2][2], sv[2][3])),
                         fmaxf(fmaxf(sv[3][0], sv[3][1]), fmaxf(sv[3][2], sv[3][3]))));
    lm = fmaxf(lm, __shfl_xor(lm, 16));
    lm = fmaxf(lm, __shfl_xor(lm, 32));
    float mnew = fmaxf(mold, lm);
    float alpha = __builtin_amdgcn_exp2f(mold - mnew);

    float p[4][4];
    float ts = 0.f;
    #pragma unroll
    for (int jb = 0; jb < 4; ++jb)
      #pragma unroll
      for (int r = 0; r < 4; ++r) {
        float pv = __builtin_amdgcn_exp2f(sv[jb][r] - mnew);
        p[jb][r] = pv; ts += pv;
      }
    ts += __shfl_xor(ts, 16);
    ts += __shfl_xor(ts, 32);
    lrun = lrun * alpha + ts;
    mold = mnew;

    // ---- P -> LDS (row = wave's i, col j = jb*16 + q4*4 + r) + alpha ----
    #pragma unroll
    for (int jb = 0; jb < 4; ++jb) {
      uint2 pk;
      pk.x = __builtin_bit_cast(unsigned, __builtin_amdgcn_cvt_pkrtz(p[jb][0], p[jb][1]));
      pk.y = __builtin_bit_cast(unsigned, __builtin_amdgcn_cvt_pkrtz(p[jb][2], p[jb][3]));
      *(uint2*)(Pcur + (myrow + l15) * 144 + jb * 32 + q4 * 8) = pk;
    }
    if (lane < 16) acur[myrow + lane] = alpha;
    __syncthreads();                       // ONE barrier per iter (ping-pong P)

    // ---- PV: wave = 64 c x 64 i; V frag reused across 4 i-tiles ----
    float av[4];
    #pragma unroll
    for (int ib = 0; ib < 4; ++ib) av[ib] = acur[ib * 16 + l15];
    #pragma unroll
    for (int ct = 0; ct < 4; ++ct)
      #pragma unroll
      for (int ib = 0; ib < 4; ++ib)
        #pragma unroll
        for (int r = 0; r < 4; ++r) acc[ct][ib][r] *= av[ib];

    #pragma unroll
    for (int ks = 0; ks < 2; ++ks) {
      f16x8 pfr[4];
      #pragma unroll
      for (int ib = 0; ib < 4; ++ib)
        pfr[ib] = *(const f16x8*)(Pcur + (ib * 16 + l15) * 144 + ks * 64 + q4 * 16);
      #pragma unroll
      for (int ct = 0; ct < 4; ++ct) {
        f16x8 vfr = *(const f16x8*)(vb + (size_t)(w * 64 + ct * 16 + l15) * N_ + jbase + ks * 32 + q4 * 8);
        #pragma unroll
        for (int ib = 0; ib < 4; ++ib)
          acc[ct][ib] = __builtin_amdgcn_mfma_f32_16x16x32_f16(vfr, pfr[ib], acc[ct][ib], 0, 0, 0);
      }
    }
  }

  // ---- epilogue: O /= l; y = gamma*O + x (fp32 to d_out) ----
  if (lane < 16) lrowl[myrow + lane] = lrun;
  __syncthreads();
  const float gamma = gptr[0];
  #pragma unroll
  for (int ib = 0; ib < 4; ++ib) {
    float linv = 1.0f / lrowl[ib * 16 + l15];
    const int i = i0 + ib * 16 + l15;
    #pragma unroll
    for (int ct = 0; ct < 4; ++ct) {
      #pragma unroll
      for (int r = 0; r < 4; ++r) {
        int c = w * 64 + ct * 16 + q4 * 4 + r;
        size_t off = ((size_t)(b * C_) + c) * N_ + i;
        float o = acc[ct][ib][r] * linv;
        yout[off] = fmaf(gamma, o, x[off]);
      }
    }
  }
}

// ---------------------------------------------------------------------------
// Kernel 5: BN statistics from fp32 y (d_out); one 1024-thr block per channel.
// ---------------------------------------------------------------------------
__global__ __launch_bounds__(1024) void bnstats_kernel(
    const float* __restrict__ y, float* __restrict__ meanw, float* __restrict__ rstdw)
{
  const int c = blockIdx.x;
  const int t = threadIdx.x;
  float s1 = 0.f, s2 = 0.f;
  #pragma unroll
  for (int b = 0; b < B_; ++b) {
    float4 v = *(const float4*)(y + ((size_t)(b * C_ + c)) * N_ + t * 4);
    s1 += v.x + v.y + v.z + v.w;
    s2 += v.x * v.x + v.y * v.y + v.z * v.z + v.w * v.w;
  }
  #pragma unroll
  for (int off = 1; off < 64; off <<= 1) {
    s1 += __shfl_xor(s1, off);
    s2 += __shfl_xor(s2, off);
  }
  __shared__ float r1[16], r2[16];
  const int wid = t >> 6;
  if ((t & 63) == 0) { r1[wid] = s1; r2[wid] = s2; }
  __syncthreads();
  if (t == 0) {
    float a1 = 0.f, a2 = 0.f;
    #pragma unroll
    for (int k = 0; k < 16; ++k) { a1 += r1[k]; a2 += r2[k]; }
    float mean = a1 * (1.0f / 32768.0f);
    float var  = a2 * (1.0f / 32768.0f) - mean * mean;
    meanw[c] = mean;
    rstdw[c] = rsqrtf(var + 1e-5f);
  }
}

// ---------------------------------------------------------------------------
// Kernel 6: BN normalize + ReLU, in-place fp32 on d_out.
// ---------------------------------------------------------------------------
__global__ __launch_bounds__(256) void bnapply_kernel(
    float* __restrict__ y,
    const float* __restrict__ meanw, const float* __restrict__ rstdw,
    const float* __restrict__ bnw, const float* __restrict__ bnb)
{
  size_t idx = (size_t)blockIdx.x * 256 + threadIdx.x;
  size_t el = idx * 8;
  int c = (int)((el >> 12) & 255);
  float sc = bnw[c] * rstdw[c];
  float sh = fmaf(-meanw[c], sc, bnb[c]);
  float4 v0 = *(const float4*)(y + el);
  float4 v1 = *(const float4*)(y + el + 4);
  v0.x = fmaxf(fmaf(v0.x, sc, sh), 0.f);
  v0.y = fmaxf(fmaf(v0.y, sc, sh), 0.f);
  v0.z = fmaxf(fmaf(v0.z, sc, sh), 0.f);
  v0.w = fmaxf(fmaf(v0.w, sc, sh), 0.f);
  v1.x = fmaxf(fmaf(v1.x, sc, sh), 0.f);
  v1.y = fmaxf(fmaf(v1.y, sc, sh), 0.f);
  v1.z = fmaxf(fmaf(v1.z, sc, sh), 0.f);
  v1.w = fmaxf(fmaf(v1.w, sc, sh), 0.f);
  *(float4*)(y + el) = v0;
  *(float4*)(y + el + 4) = v1;
}

extern "C" void kernel_launch(void* const* d_in, const int* in_sizes, int n_in,
                              void* d_out, int out_size, void* d_ws, size_t ws_size,
                              hipStream_t stream)
{
  const float* x   = (const float*)d_in[0];
  const float* wq  = (const float*)d_in[1];
  const float* bq  = (const float*)d_in[2];
  const float* wk  = (const float*)d_in[3];
  const float* bk  = (const float*)d_in[4];
  const float* wv  = (const float*)d_in[5];
  const float* bv  = (const float*)d_in[6];
  const float* gm  = (const float*)d_in[7];
  const float* bnw = (const float*)d_in[8];
  const float* bnb = (const float*)d_in[9];

  // d_out: xT fp16 [0:16.78MB] during stages 1-3, then y fp32 (33.55MB).
  _Float16* xT = (_Float16*)d_out;
  float* y = (float*)d_out;

  // ws (~22 MB): qf | kf | vfp | wf | meanw | rstdw
  char* ws = (char*)d_ws;
  _Float16* qf  = (_Float16*)(ws);
  _Float16* kf  = (_Float16*)(ws + ((size_t)2 << 20));
  _Float16* vfp = (_Float16*)(ws + ((size_t)4 << 20));
  _Float16* wf  = (_Float16*)(ws + ((size_t)21 << 20));
  float* meanw  = (float*)(ws + ((size_t)22 << 20));
  float* rstdw  = (float*)(ws + ((size_t)22 << 20) + 4096);

  hipLaunchKernelGGL(xpose_kernel, dim3(1024), dim3(256), 0, stream, x, xT);
  hipLaunchKernelGGL(wconv_kernel, dim3(80), dim3(256), 0, stream, wq, wk, wv, wf);
  hipLaunchKernelGGL(proj_gemm_kernel, dim3(1280), dim3(256), 0, stream,
                     xT, wf, bq, bk, bv, qf, kf, vfp);
  hipLaunchKernelGGL(attn_kernel, dim3(512), dim3(256), 0, stream,
                     x, gm, qf, kf, vfp, y);
  hipLaunchKernelGGL(bnstats_kernel, dim3(256), dim3(1024), 0, stream,
                     y, meanw, rstdw);
  hipLaunchKernelGGL(bnapply_kernel, dim3(4096), dim3(256), 0, stream,
                     y, meanw, rstdw, bnw, bnb);
}